// Round 3
// baseline (74.226 us; speedup 1.0000x reference)
//
#include <hip/hip_runtime.h>

// CAM: out = (q @ k^T) @ v + v  ==  q @ (k^T @ v) + v.   S[b] = k^T v is 49x49.
//   ktv : partial S per (batch,split). K rows broadcast from LDS, V coalesced.
//   sred: sum split partials -> padded S[49][52] per batch.
//   qs  : out = q @ S + v. q rows broadcast from LDS, S cols in VGPRs, IO coalesced.

#define BATCH  128
#define CH     1024
#define NN     49
#define NPAD   52
#define SPLITB 4
#define KCH    (CH / SPLITB)   // 256 channels per ktv block
#define KHALF  128             // channels staged per LDS half

// ---------------- Kernel 1: Spart[b*SPLITB+s] = K-chunk^T @ V-chunk ---------
__global__ __launch_bounds__(512) void ktv_kernel(
    const float* __restrict__ Kg, const float* __restrict__ Vg,
    float* __restrict__ Spart) {
  const int blk = blockIdx.x;
  const int b   = blk / SPLITB;
  const int s   = blk - b * SPLITB;
  const int tid = threadIdx.x;
  const int wv  = __builtin_amdgcn_readfirstlane(tid >> 6);
  const int lane = tid & 63;
  const bool act = lane < NN;

  // union: K-stage (128*52 = 6656 f) and 4 reduction buffers (4*49*64 = 12544 f)
  __shared__ __align__(16) float lds[4 * NN * 64];

  const float* Vb = Vg + (size_t)b * CH * NN;

  float acc[NN];
  #pragma unroll
  for (int i = 0; i < NN; ++i) acc[i] = 0.f;

  for (int half = 0; half < 2; ++half) {
    const int c0h = s * KCH + half * KHALF;
    const float* Ksrc = Kg + ((size_t)b * CH + c0h) * NN;
    for (int idx = tid; idx < KHALF * NN; idx += 512) {
      const int r = idx / NN, m = idx - r * NN;
      lds[r * NPAD + m] = Ksrc[idx];          // coalesced read, LDS scatter
    }
    __syncthreads();
    const int ccb = wv * 16;                  // 16 channels per wave per half
    #pragma unroll 2
    for (int ci = 0; ci < 16; ++ci) {
      const int cc = ccb + ci;
      const float vj = act ? Vb[(size_t)(c0h + cc) * NN + lane] : 0.f;
      #pragma unroll
      for (int g = 0; g < 12; ++g) {
        const float4 kv = *(const float4*)&lds[cc * NPAD + 4 * g];
        acc[4 * g + 0] = fmaf(kv.x, vj, acc[4 * g + 0]);
        acc[4 * g + 1] = fmaf(kv.y, vj, acc[4 * g + 1]);
        acc[4 * g + 2] = fmaf(kv.z, vj, acc[4 * g + 2]);
        acc[4 * g + 3] = fmaf(kv.w, vj, acc[4 * g + 3]);
      }
      acc[48] = fmaf(lds[cc * NPAD + 48], vj, acc[48]);
    }
    __syncthreads();
  }

  // reduce 8 wave-partials pairwise in LDS
  if (wv < 4) {
    #pragma unroll
    for (int i = 0; i < NN; ++i) lds[wv * (NN * 64) + i * 64 + lane] = acc[i];
  }
  __syncthreads();
  if (wv >= 4) {
    #pragma unroll
    for (int i = 0; i < NN; ++i) lds[(wv - 4) * (NN * 64) + i * 64 + lane] += acc[i];
  }
  __syncthreads();

  float* Sp = Spart + (size_t)blk * (NN * NN);
  for (int e = tid; e < NN * NN; e += 512) {
    const int i = e / NN, j = e - i * NN;
    Sp[e] = (lds[0 * (NN * 64) + i * 64 + j] + lds[1 * (NN * 64) + i * 64 + j]) +
            (lds[2 * (NN * 64) + i * 64 + j] + lds[3 * (NN * 64) + i * 64 + j]);
  }
}

// ---------------- Kernel 2: S[b] = sum_s Spart, padded to 49x52 -------------
__global__ __launch_bounds__(256) void sred_kernel(
    const float* __restrict__ Spart, float* __restrict__ Sg) {
  const int b = blockIdx.x;
  const int t = threadIdx.x;
  for (int e = t; e < NN * NPAD; e += 256) {
    const int m = e / NPAD, n = e - m * NPAD;
    float v = 0.f;
    if (n < NN) {
      #pragma unroll
      for (int s = 0; s < SPLITB; ++s)
        v += Spart[(size_t)(b * SPLITB + s) * (NN * NN) + m * NN + n];
    }
    Sg[(size_t)b * (NN * NPAD) + e] = v;
  }
}

// ---------------- Kernel 3: out[b,r,:] = q[b,r,:] @ S[b] + v[b,r,:] ---------
// lane = n. S column in 49 VGPRs. q rows broadcast via LDS ds_read_b128.
#define QR 32          // rows per block (4 waves x 8 rows)

__global__ __launch_bounds__(256) void qs_kernel(
    const float* __restrict__ Qg, const float* __restrict__ Vg,
    const float* __restrict__ Sg, float* __restrict__ Og) {
  const int blk  = blockIdx.x;
  const int bpb  = CH / QR;                   // 32 blocks per batch
  const int b    = blk / bpb;
  const int rblk = blk - b * bpb;
  const int tid  = threadIdx.x;
  const int wv   = __builtin_amdgcn_readfirstlane(tid >> 6);
  const int n    = tid & 63;
  const bool act = n < NN;

  __shared__ __align__(16) float Qlds[QR * NPAD];

  // stage this block's 32 q-rows (coalesced global reads)
  const int r0 = rblk * QR;
  const float* Qsrc = Qg + ((size_t)b * CH + r0) * NN;
  for (int idx = tid; idx < QR * NN; idx += 256) {
    const int r = idx / NN, m = idx - r * NN;
    Qlds[r * NPAD + m] = Qsrc[idx];
  }

  // load my S column (coalesced, L2-resident)
  const float* Sb = Sg + (size_t)b * (NN * NPAD);
  float sc[NN];
  #pragma unroll
  for (int m = 0; m < NN; ++m) sc[m] = act ? Sb[m * NPAD + n] : 0.f;

  __syncthreads();

  const size_t base = (size_t)b * CH * NN;
  #pragma unroll 2
  for (int rr = 0; rr < QR / 4; ++rr) {
    const int r = wv * (QR / 4) + rr;
    float a0 = 0.f, a1 = 0.f, a2 = 0.f, a3 = 0.f;
    #pragma unroll
    for (int g = 0; g < 12; ++g) {
      const float4 qv = *(const float4*)&Qlds[r * NPAD + 4 * g];  // broadcast
      a0 = fmaf(qv.x, sc[4 * g + 0], a0);
      a1 = fmaf(qv.y, sc[4 * g + 1], a1);
      a2 = fmaf(qv.z, sc[4 * g + 2], a2);
      a3 = fmaf(qv.w, sc[4 * g + 3], a3);
    }
    a0 = fmaf(Qlds[r * NPAD + 48], sc[48], a0);
    const float acc = (a0 + a1) + (a2 + a3);
    const size_t off = base + (size_t)(r0 + r) * NN + n;
    if (act) Og[off] = acc + Vg[off];          // coalesced 196B per wave
  }
}

extern "C" void kernel_launch(void* const* d_in, const int* in_sizes, int n_in,
                              void* d_out, int out_size, void* d_ws, size_t ws_size,
                              hipStream_t stream) {
  (void)in_sizes; (void)n_in; (void)out_size; (void)ws_size;
  const float* v1 = (const float*)d_in[0];
  const float* q1 = (const float*)d_in[1];
  const float* k1 = (const float*)d_in[2];
  float* out = (float*)d_out;

  float* spart = (float*)d_ws;                                 // 512*2401*4 = 4.92 MB
  float* sg    = spart + (size_t)BATCH * SPLITB * NN * NN;     // 128*49*52*4 = 1.30 MB

  ktv_kernel<<<dim3(BATCH * SPLITB), dim3(512), 0, stream>>>(k1, v1, spart);
  sred_kernel<<<dim3(BATCH), dim3(256), 0, stream>>>(spart, sg);
  qs_kernel<<<dim3(BATCH * (CH / QR)), dim3(256), 0, stream>>>(q1, v1, sg, out);
}

// Round 4
// 63.909 us; speedup vs baseline: 1.1614x; 1.1614x over previous
//
#include <hip/hip_runtime.h>

// CAM: out = (q @ k^T) @ v + v  ==  q @ (k^T @ v) + v.   S[b] = k^T v is 49x49.
//   ktv : partial S per (batch,split). K rows via SGPR broadcast (s_load),
//         V coalesced per lane (lane = column j), 49 acc regs per lane.
//         [R2 version — R3's LDS-broadcast variant cost 5x: LDS return BW
//          is consumed per-instruction even for same-address broadcast.]
//   sred: sum split partials -> padded S[49][52] per batch.
//   qs  : out = q @ S + v. q rows broadcast from LDS, S cols in VGPRs,
//         fully coalesced global IO. [R3 version — beat s_load variant 2x.]

#define BATCH  128
#define CH     1024
#define NN     49
#define NPAD   52
#define SPLITB 4
#define WAVES_K 8                          // ktv: 512 threads = 8 waves
#define CCHUNK (CH / (SPLITB * WAVES_K))   // 32 channels per wave

// ---------------- Kernel 1: Spart[b*SPLITB+s] = K-chunk^T @ V-chunk ---------
__global__ __launch_bounds__(512) void ktv_kernel(
    const float* __restrict__ Kg, const float* __restrict__ Vg,
    float* __restrict__ Spart) {
  const int blk = blockIdx.x;
  const int b   = blk / SPLITB;
  const int s   = blk - b * SPLITB;
  const int tid = threadIdx.x;
  const int wv  = __builtin_amdgcn_readfirstlane(tid >> 6);
  const int lane = tid & 63;
  const bool act = lane < NN;

  const float* Kb = Kg + (size_t)b * CH * NN;
  const float* Vb = Vg + (size_t)b * CH * NN;
  const int c0 = s * (CH / SPLITB) + wv * CCHUNK;

  float acc[NN];
  #pragma unroll
  for (int i = 0; i < NN; ++i) acc[i] = 0.f;

  #pragma unroll 2
  for (int cc = 0; cc < CCHUNK; ++cc) {
    const int c = c0 + cc;
    const float* kr = Kb + (size_t)c * NN;     // wave-uniform -> s_load
    const float vj = act ? Vb[(size_t)c * NN + lane] : 0.f;  // coalesced
    #pragma unroll
    for (int i = 0; i < NN; ++i) acc[i] = fmaf(kr[i], vj, acc[i]);
  }

  // reduce 8 wave-partials (4 LDS buffers, waves 4-7 add into 0-3)
  __shared__ float red[4][NN * 64];
  if (wv < 4) {
    #pragma unroll
    for (int i = 0; i < NN; ++i) red[wv][i * 64 + lane] = acc[i];
  }
  __syncthreads();
  if (wv >= 4) {
    #pragma unroll
    for (int i = 0; i < NN; ++i) red[wv - 4][i * 64 + lane] += acc[i];
  }
  __syncthreads();

  float* Sp = Spart + (size_t)blk * (NN * NN);
  for (int e = tid; e < NN * NN; e += 512) {
    const int i = e / NN, j = e - i * NN;
    Sp[e] = (red[0][i * 64 + j] + red[1][i * 64 + j]) +
            (red[2][i * 64 + j] + red[3][i * 64 + j]);
  }
}

// ---------------- Kernel 2: S[b] = sum_s Spart, padded to 49x52 -------------
__global__ __launch_bounds__(256) void sred_kernel(
    const float* __restrict__ Spart, float* __restrict__ Sg) {
  const int b = blockIdx.x;
  const int t = threadIdx.x;
  for (int e = t; e < NN * NPAD; e += 256) {
    const int m = e / NPAD, n = e - m * NPAD;
    float v = 0.f;
    if (n < NN) {
      #pragma unroll
      for (int s = 0; s < SPLITB; ++s)
        v += Spart[(size_t)(b * SPLITB + s) * (NN * NN) + m * NN + n];
    }
    Sg[(size_t)b * (NN * NPAD) + e] = v;
  }
}

// ---------------- Kernel 3: out[b,r,:] = q[b,r,:] @ S[b] + v[b,r,:] ---------
// lane = n. S column in 49 VGPRs. q rows broadcast via LDS ds_read_b128.
#define QR 32          // rows per block (4 waves x 8 rows)

__global__ __launch_bounds__(256) void qs_kernel(
    const float* __restrict__ Qg, const float* __restrict__ Vg,
    const float* __restrict__ Sg, float* __restrict__ Og) {
  const int blk  = blockIdx.x;
  const int bpb  = CH / QR;                   // 32 blocks per batch
  const int b    = blk / bpb;
  const int rblk = blk - b * bpb;
  const int tid  = threadIdx.x;
  const int wv   = __builtin_amdgcn_readfirstlane(tid >> 6);
  const int n    = tid & 63;
  const bool act = n < NN;

  __shared__ __align__(16) float Qlds[QR * NPAD];

  // stage this block's 32 q-rows (coalesced global reads)
  const int r0 = rblk * QR;
  const float* Qsrc = Qg + ((size_t)b * CH + r0) * NN;
  for (int idx = tid; idx < QR * NN; idx += 256) {
    const int r = idx / NN, m = idx - r * NN;
    Qlds[r * NPAD + m] = Qsrc[idx];
  }

  // load my S column (coalesced, L2-resident)
  const float* Sb = Sg + (size_t)b * (NN * NPAD);
  float sc[NN];
  #pragma unroll
  for (int m = 0; m < NN; ++m) sc[m] = act ? Sb[m * NPAD + n] : 0.f;

  __syncthreads();

  const size_t base = (size_t)b * CH * NN;
  #pragma unroll 2
  for (int rr = 0; rr < QR / 4; ++rr) {
    const int r = wv * (QR / 4) + rr;
    float a0 = 0.f, a1 = 0.f, a2 = 0.f, a3 = 0.f;
    #pragma unroll
    for (int g = 0; g < 12; ++g) {
      const float4 qv = *(const float4*)&Qlds[r * NPAD + 4 * g];  // broadcast
      a0 = fmaf(qv.x, sc[4 * g + 0], a0);
      a1 = fmaf(qv.y, sc[4 * g + 1], a1);
      a2 = fmaf(qv.z, sc[4 * g + 2], a2);
      a3 = fmaf(qv.w, sc[4 * g + 3], a3);
    }
    a0 = fmaf(Qlds[r * NPAD + 48], sc[48], a0);
    const float acc = (a0 + a1) + (a2 + a3);
    const size_t off = base + (size_t)(r0 + r) * NN + n;
    if (act) Og[off] = acc + Vg[off];          // coalesced 196B per wave
  }
}

extern "C" void kernel_launch(void* const* d_in, const int* in_sizes, int n_in,
                              void* d_out, int out_size, void* d_ws, size_t ws_size,
                              hipStream_t stream) {
  (void)in_sizes; (void)n_in; (void)out_size; (void)ws_size;
  const float* v1 = (const float*)d_in[0];
  const float* q1 = (const float*)d_in[1];
  const float* k1 = (const float*)d_in[2];
  float* out = (float*)d_out;

  float* spart = (float*)d_ws;                                 // 512*2401*4 = 4.92 MB
  float* sg    = spart + (size_t)BATCH * SPLITB * NN * NN;     // 128*49*52*4 = 1.30 MB

  ktv_kernel<<<dim3(BATCH * SPLITB), dim3(512), 0, stream>>>(k1, v1, spart);
  sred_kernel<<<dim3(BATCH), dim3(256), 0, stream>>>(spart, sg);
  qs_kernel<<<dim3(BATCH * (CH / QR)), dim3(256), 0, stream>>>(q1, v1, sg, out);
}